// Round 1
// baseline (645.715 us; speedup 1.0000x reference)
//
#include <hip/hip_runtime.h>
#include <math.h>

// DCTFreqConv: fused 8x8 DCT -> 64ch conv1d(win3, end-pad 2) over flattened
// freq axis -> inverse 8x8 DCT.  x:(8,64,256,256) f32, w:(64,64,3), b:(64,)
//
// 1 WG = (bz, by, 4 bx blocks). 256 threads.
// Phase A: stage weights into LDS as W[i][w][o]  (conflict-free broadcast reads)
// Phase B: thread (c,blk) loads 8x8 spatial block (float4), fwd DCT in regs,
//          stores 64 coefs + 4 zero-pad to LDS Cf[c][blk][68].
// Phase C: thread (o,blk): conv over i with row-in-registers (17x ds_read_b128
//          per 192 FMAs), 64 accumulators.
// Phase D: inverse DCT in regs, float4 stores.

#define BSZ 8
#define CH 64
#define HW 256
#define NBLK 32
#define NB 4
#define THREADS 256

#define W_LDS (64 * 3 * 64)          // floats
#define CF_STRIDE 68                 // 16B-aligned rows (68*4 = 272B)
#define CF_LDS (64 * NB * CF_STRIDE) // floats

__global__ __launch_bounds__(THREADS, 1)
void dct_freq_conv_kernel(const float* __restrict__ x,
                          const float* __restrict__ conv_w,
                          const float* __restrict__ conv_b,
                          float* __restrict__ out)
{
    extern __shared__ float smem[];
    float* Wl = smem;                 // [r=i*3+w][o]
    float* Cf = smem + W_LDS;         // [(c*NB+blk)*CF_STRIDE + t]

    const int tid = threadIdx.x;
    const int bz  = blockIdx.z;
    const int by  = blockIdx.y;
    const int bx0 = blockIdx.x * NB;

    const int c   = tid >> 2;   // channel in phase B, out-channel in phase C
    const int blk = tid & 3;

    // --- DCT matrix in registers (orthonormal DCT-II, 8x8) ---
    float Dmr[8][8];
    #pragma unroll
    for (int k = 0; k < 8; ++k) {
        #pragma unroll
        for (int n = 0; n < 8; ++n) {
            float v = 0.5f * cosf((float)M_PI * (float)((2 * n + 1) * k) / 16.0f);
            if (k == 0) v = 0.35355339059327373f;  // 0.5/sqrt(2)
            Dmr[k][n] = v;
        }
    }

    // --- Phase A: stage conv weights, re-laid as Wl[i*3+w][o] ---
    // conv_w flat index = o*192 + (i*3+w)
    #pragma unroll 4
    for (int j = 0; j < 48; ++j) {
        int f = j * 256 + tid;
        int o = f / 192;
        int r = f - o * 192;
        Wl[r * 64 + o] = conv_w[f];
    }

    // --- Phase B: load 8x8 block, forward DCT, store to LDS ---
    {
        const float* xp = x + ((((size_t)bz * CH + c) * HW + by * 8) * HW
                               + (bx0 + blk) * 8);
        float blkv[8][8];
        #pragma unroll
        for (int r = 0; r < 8; ++r) {
            float4 a = *reinterpret_cast<const float4*>(xp + r * HW);
            float4 b = *reinterpret_cast<const float4*>(xp + r * HW + 4);
            blkv[r][0] = a.x; blkv[r][1] = a.y; blkv[r][2] = a.z; blkv[r][3] = a.w;
            blkv[r][4] = b.x; blkv[r][5] = b.y; blkv[r][6] = b.z; blkv[r][7] = b.w;
        }
        // tmp = blk * D^T   (tmp[n][l] = sum_m blk[n][m] * D[l][m])
        float tmp[8][8];
        #pragma unroll
        for (int n = 0; n < 8; ++n) {
            #pragma unroll
            for (int l = 0; l < 8; ++l) {
                float s = 0.f;
                #pragma unroll
                for (int m = 0; m < 8; ++m) s = fmaf(blkv[n][m], Dmr[l][m], s);
                tmp[n][l] = s;
            }
        }
        // coef = D * tmp
        float* cfrow = Cf + (c * NB + blk) * CF_STRIDE;
        #pragma unroll
        for (int k = 0; k < 8; ++k) {
            #pragma unroll
            for (int l = 0; l < 8; ++l) {
                float s = 0.f;
                #pragma unroll
                for (int n = 0; n < 8; ++n) s = fmaf(Dmr[k][n], tmp[n][l], s);
                cfrow[k * 8 + l] = s;
            }
        }
        cfrow[64] = 0.f; cfrow[65] = 0.f; cfrow[66] = 0.f; cfrow[67] = 0.f;
    }

    __syncthreads();

    // --- Phase C: conv1d across channels.  thread = (o=c, blk). ---
    float acc[64];
    #pragma unroll
    for (int t = 0; t < 64; ++t) acc[t] = 0.f;

    for (int i = 0; i < 64; ++i) {
        const float* crow = Cf + (i * NB + blk) * CF_STRIDE;
        float row[68];
        #pragma unroll
        for (int j = 0; j < 17; ++j) {
            float4 v = *reinterpret_cast<const float4*>(crow + j * 4);
            row[4 * j + 0] = v.x; row[4 * j + 1] = v.y;
            row[4 * j + 2] = v.z; row[4 * j + 3] = v.w;
        }
        const float w0 = Wl[(i * 3 + 0) * 64 + c];
        const float w1 = Wl[(i * 3 + 1) * 64 + c];
        const float w2 = Wl[(i * 3 + 2) * 64 + c];
        #pragma unroll
        for (int t = 0; t < 64; ++t)
            acc[t] = fmaf(w0, row[t],
                     fmaf(w1, row[t + 1],
                     fmaf(w2, row[t + 2], acc[t])));
    }

    // bias (zeros in this problem, but keep general)
    {
        const float bias = conv_b[c];
        #pragma unroll
        for (int t = 0; t < 64; ++t) acc[t] += bias;
    }

    // --- Phase D: inverse DCT (img = D^T * y * D), float4 stores ---
    float tmp2[8][8];  // tmp2[n][l] = sum_k D[k][n] * y[k][l]
    #pragma unroll
    for (int n = 0; n < 8; ++n) {
        #pragma unroll
        for (int l = 0; l < 8; ++l) {
            float s = 0.f;
            #pragma unroll
            for (int k = 0; k < 8; ++k) s = fmaf(Dmr[k][n], acc[k * 8 + l], s);
            tmp2[n][l] = s;
        }
    }
    float* op = out + ((((size_t)bz * CH + c) * HW + by * 8) * HW
                       + (bx0 + blk) * 8);
    #pragma unroll
    for (int n = 0; n < 8; ++n) {
        float o8[8];
        #pragma unroll
        for (int m = 0; m < 8; ++m) {
            float s = 0.f;
            #pragma unroll
            for (int l = 0; l < 8; ++l) s = fmaf(tmp2[n][l], Dmr[l][m], s);
            o8[m] = s;
        }
        *reinterpret_cast<float4*>(op + n * HW)     = make_float4(o8[0], o8[1], o8[2], o8[3]);
        *reinterpret_cast<float4*>(op + n * HW + 4) = make_float4(o8[4], o8[5], o8[6], o8[7]);
    }
}

extern "C" void kernel_launch(void* const* d_in, const int* in_sizes, int n_in,
                              void* d_out, int out_size, void* d_ws, size_t ws_size,
                              hipStream_t stream) {
    const float* x  = (const float*)d_in[0];
    const float* cw = (const float*)d_in[1];
    const float* cb = (const float*)d_in[2];
    float* o        = (float*)d_out;

    const size_t lds_bytes = (size_t)(W_LDS + CF_LDS) * sizeof(float); // 118784 B
    hipFuncSetAttribute(reinterpret_cast<const void*>(dct_freq_conv_kernel),
                        hipFuncAttributeMaxDynamicSharedMemorySize,
                        (int)lds_bytes);

    dim3 grid(NBLK / NB, NBLK, BSZ);  // (8, 32, 8) = 2048 WGs
    dct_freq_conv_kernel<<<grid, dim3(THREADS), lds_bytes, stream>>>(x, cw, cb, o);
}

// Round 2
// 258.797 us; speedup vs baseline: 2.4951x; 2.4951x over previous
//
#include <hip/hip_runtime.h>

// DCTFreqConv fused: 8x8 fwd DCT (fp32 VALU) -> 64ch conv1d win3 as bf16 MFMA
// (3 shifted GEMMs) -> 8x8 inv DCT (fp32 VALU).
// x:(8,64,256,256) f32, w:(64,64,3), b:(64,) -> out:(8,64,256,256) f32
//
// 1 WG = (bz, by, 4 bx blocks), 256 threads, wave w owns sample (bx0+w).
// LDS: Wb[64][200] bf16 (W re-laid [o][w*64+i], pad stride) = 25600 B
//      Ct[4][66][72] bf16 (coef transposed [t][i], rows 64,65 = zero pad) = 38016 B
//      biasL[64] f32 = 256 B. Total 63872 B -> 2 WG/CU.

#define THREADS 256
#define HW 256
#define CH 64
#define W_STRIDE 200
#define CT_ROW 72
#define CT_SAMPLE (66 * CT_ROW)
#define WB_USHORTS (64 * W_STRIDE)

typedef __attribute__((ext_vector_type(8))) short short8b;
typedef __attribute__((ext_vector_type(4))) float f32x4;
typedef __attribute__((ext_vector_type(4))) unsigned short us4;

__device__ inline unsigned short f2bf(float f) {
    unsigned u = __builtin_bit_cast(unsigned, f);
    u += 0x7FFFu + ((u >> 16) & 1u);
    return (unsigned short)(u >> 16);
}
__device__ inline float bf2f(unsigned short h) {
    unsigned u = ((unsigned)h) << 16;
    return __builtin_bit_cast(float, u);
}

// Orthonormal 8-point DCT-II matrix (row k, col n). Compile-time constants.
__device__ __constant__ static const float D8[8][8] = {
  { 0.3535533906f, 0.3535533906f, 0.3535533906f, 0.3535533906f, 0.3535533906f, 0.3535533906f, 0.3535533906f, 0.3535533906f },
  { 0.4903926402f, 0.4157348062f, 0.2777851165f, 0.0975451610f,-0.0975451610f,-0.2777851165f,-0.4157348062f,-0.4903926402f },
  { 0.4619397663f, 0.1913417162f,-0.1913417162f,-0.4619397663f,-0.4619397663f,-0.1913417162f, 0.1913417162f, 0.4619397663f },
  { 0.4157348062f,-0.0975451610f,-0.4903926402f,-0.2777851165f, 0.2777851165f, 0.4903926402f, 0.0975451610f,-0.4157348062f },
  { 0.3535533906f,-0.3535533906f,-0.3535533906f, 0.3535533906f, 0.3535533906f,-0.3535533906f,-0.3535533906f, 0.3535533906f },
  { 0.2777851165f,-0.4903926402f, 0.0975451610f, 0.4157348062f,-0.4157348062f,-0.0975451610f, 0.4903926402f,-0.2777851165f },
  { 0.1913417162f,-0.4619397663f, 0.4619397663f,-0.1913417162f,-0.1913417162f, 0.4619397663f,-0.4619397663f, 0.1913417162f },
  { 0.0975451610f,-0.2777851165f, 0.4157348062f,-0.4903926402f, 0.4903926402f,-0.4157348062f, 0.2777851165f,-0.0975451610f },
};

__global__ __launch_bounds__(THREADS, 2)
void dct_freq_conv_kernel(const float* __restrict__ x,
                          const float* __restrict__ conv_w,
                          const float* __restrict__ conv_b,
                          float* __restrict__ out)
{
    extern __shared__ char smem[];
    unsigned short* Wb    = (unsigned short*)smem;                       // [64][200]
    unsigned short* Ct    = (unsigned short*)(smem + 2 * WB_USHORTS);    // [4][66][72]
    float*          biasL = (float*)(smem + 2 * WB_USHORTS + 2 * 4 * CT_SAMPLE);

    const int tid = threadIdx.x;
    const int bz  = blockIdx.z;
    const int by  = blockIdx.y;
    const int bx0 = blockIdx.x * 4;

    const int c   = tid >> 2;   // channel (phase B), out-channel (phase D)
    const int blk = tid & 3;    // sample-within-WG

    // ---- Phase A: stage weights (bf16, re-laid), bias, zero pad rows ----
    #pragma unroll 4
    for (int j = tid; j < 64 * 192; j += THREADS) {
        int o = j / 192;
        int r = j - o * 192;        // r = i*3 + w
        int i = r / 3;
        int w = r - i * 3;
        Wb[o * W_STRIDE + w * 64 + i] = f2bf(conv_w[j]);
    }
    if (tid < 64) biasL[tid] = conv_b[tid];
    {   // zero pad rows t=64,65 for each of 4 samples
        int s = tid >> 6, i = tid & 63;
        Ct[s * CT_SAMPLE + 64 * CT_ROW + i] = 0;
        Ct[s * CT_SAMPLE + 65 * CT_ROW + i] = 0;
    }

    // ---- Phase B: load 8x8 block, fwd DCT (in-place, const D8), write Ct ----
    {
        const float* xp = x + ((((size_t)bz * CH + c) * HW + by * 8) * HW
                               + (bx0 + blk) * 8);
        float v[8][8];
        #pragma unroll
        for (int r = 0; r < 8; ++r) {
            float4 a = *reinterpret_cast<const float4*>(xp + r * HW);
            float4 b = *reinterpret_cast<const float4*>(xp + r * HW + 4);
            v[r][0] = a.x; v[r][1] = a.y; v[r][2] = a.z; v[r][3] = a.w;
            v[r][4] = b.x; v[r][5] = b.y; v[r][6] = b.z; v[r][7] = b.w;
        }
        // row transform: v[n][:] <- v[n][:] * D^T
        #pragma unroll
        for (int n = 0; n < 8; ++n) {
            float r[8];
            #pragma unroll
            for (int l = 0; l < 8; ++l) {
                float s = 0.f;
                #pragma unroll
                for (int m = 0; m < 8; ++m) s = fmaf(v[n][m], D8[l][m], s);
                r[l] = s;
            }
            #pragma unroll
            for (int l = 0; l < 8; ++l) v[n][l] = r[l];
        }
        // col transform + transposed bf16 store: Ct[t=k*8+l][i=c]
        unsigned short* ctw = Ct + blk * CT_SAMPLE + c;
        #pragma unroll
        for (int l = 0; l < 8; ++l) {
            #pragma unroll
            for (int k = 0; k < 8; ++k) {
                float s = 0.f;
                #pragma unroll
                for (int n = 0; n < 8; ++n) s = fmaf(D8[k][n], v[n][l], s);
                ctw[(k * 8 + l) * CT_ROW] = f2bf(s);
            }
        }
    }

    __syncthreads();

    // ---- Phase C: conv as 3 shifted GEMMs via bf16 MFMA. Wave = 1 sample ----
    const int wid  = tid >> 6;
    const int lane = tid & 63;
    const int lr   = lane & 15;
    const int lq   = lane >> 4;

    f32x4 acc[4][4];
    #pragma unroll
    for (int m = 0; m < 4; ++m)
        #pragma unroll
        for (int n = 0; n < 4; ++n)
            acc[m][n] = (f32x4){0.f, 0.f, 0.f, 0.f};

    unsigned short* CtP = Ct + wid * CT_SAMPLE;

    #pragma unroll
    for (int kc = 0; kc < 6; ++kc) {
        const int w  = kc >> 1;
        const int i0 = (kc & 1) * 32 + 8 * lq;
        short8b a[4], b[4];
        #pragma unroll
        for (int m = 0; m < 4; ++m)
            a[m] = *(const short8b*)&Wb[(m * 16 + lr) * W_STRIDE + w * 64 + i0];
        #pragma unroll
        for (int n = 0; n < 4; ++n)
            b[n] = *(const short8b*)&CtP[(n * 16 + lr + w) * CT_ROW + i0];
        #pragma unroll
        for (int m = 0; m < 4; ++m)
            #pragma unroll
            for (int n = 0; n < 4; ++n)
                acc[m][n] = __builtin_amdgcn_mfma_f32_16x16x32_bf16(
                    a[m], b[n], acc[m][n], 0, 0, 0);
    }

    // Write Y[t][o] bf16, overwriting own sample's Ct region (wave-local, safe).
    #pragma unroll
    for (int mt = 0; mt < 4; ++mt) {
        const int o0 = mt * 16 + lq * 4;
        #pragma unroll
        for (int nt = 0; nt < 4; ++nt) {
            const int t = nt * 16 + lr;
            us4 pk;
            #pragma unroll
            for (int j = 0; j < 4; ++j)
                pk[j] = f2bf(acc[mt][nt][j] + biasL[o0 + j]);
            *(us4*)&CtP[t * CT_ROW + o0] = pk;
        }
    }

    __syncthreads();

    // ---- Phase D: inv DCT per (o=c, blk), fp32, coalesced stores ----
    {
        const unsigned short* yb = Ct + blk * CT_SAMPLE + c;
        float y[64];
        #pragma unroll
        for (int t = 0; t < 64; ++t) y[t] = bf2f(yb[t * CT_ROW]);

        // col transform in place: y[n*8+l] <- sum_k D8[k][n] * y[k*8+l]
        #pragma unroll
        for (int l = 0; l < 8; ++l) {
            float r[8];
            #pragma unroll
            for (int n = 0; n < 8; ++n) {
                float s = 0.f;
                #pragma unroll
                for (int k = 0; k < 8; ++k) s = fmaf(D8[k][n], y[k * 8 + l], s);
                r[n] = s;
            }
            #pragma unroll
            for (int n = 0; n < 8; ++n) y[n * 8 + l] = r[n];
        }
        float* op = out + ((((size_t)bz * CH + c) * HW + by * 8) * HW
                           + (bx0 + blk) * 8);
        #pragma unroll
        for (int n = 0; n < 8; ++n) {
            float o8[8];
            #pragma unroll
            for (int m = 0; m < 8; ++m) {
                float s = 0.f;
                #pragma unroll
                for (int l = 0; l < 8; ++l) s = fmaf(y[n * 8 + l], D8[l][m], s);
                o8[m] = s;
            }
            *reinterpret_cast<float4*>(op + n * HW)     = make_float4(o8[0], o8[1], o8[2], o8[3]);
            *reinterpret_cast<float4*>(op + n * HW + 4) = make_float4(o8[4], o8[5], o8[6], o8[7]);
        }
    }
}

extern "C" void kernel_launch(void* const* d_in, const int* in_sizes, int n_in,
                              void* d_out, int out_size, void* d_ws, size_t ws_size,
                              hipStream_t stream) {
    const float* x  = (const float*)d_in[0];
    const float* cw = (const float*)d_in[1];
    const float* cb = (const float*)d_in[2];
    float* o        = (float*)d_out;

    const size_t lds_bytes = 2 * WB_USHORTS + 2 * 4 * CT_SAMPLE + 64 * sizeof(float); // 63872
    hipFuncSetAttribute(reinterpret_cast<const void*>(dct_freq_conv_kernel),
                        hipFuncAttributeMaxDynamicSharedMemorySize,
                        (int)lds_bytes);

    dim3 grid(8, 32, 8);  // (bx/4, by, bz) = 2048 WGs
    dct_freq_conv_kernel<<<grid, dim3(THREADS), lds_bytes, stream>>>(x, cw, cb, o);
}